// Round 13
// baseline (2821.061 us; speedup 1.0000x reference)
//
#include <hip/hip_runtime.h>
#include <cstdint>
#include <cstddef>

#define B_   64
#define T_   512
#define E_   512
#define H_   1024
#define G4_  4096
#define KTOT 1536
#define NWG  256

typedef float f32x4 __attribute__((ext_vector_type(4)));
typedef int   i32x4 __attribute__((ext_vector_type(4)));

#define OFF_XE    ((size_t)0)
#define OFF_WC    (OFF_XE + (size_t)T_*B_*E_*2)     // 32 MB
#define OFF_BIAS  (OFF_WC + (size_t)G4_*KTOT*2)     // +12.6 MB
#define OFF_H0    (OFF_BIAS + (size_t)G4_*4)
#define OFF_FLAGS (OFF_H0 + (size_t)B_*H_*2)
#define OFF_HBT   (OFF_FLAGS + (size_t)16384)       // bf16 h history, 64 MB

__device__ __forceinline__ unsigned short f2b(float f) {
    unsigned u = __float_as_uint(f);
    return (unsigned short)((u + 0x7fffu + ((u >> 16) & 1u)) >> 16);  // RNE
}

// Permuted combined weights: permuted row p = s*64 + q*16 + hl  <->
// original gate row q*1024 + s*16 + hl (q: i,f,g,o; s: 16-hdim block).
__global__ void prep_w(const float* __restrict__ wih, const float* __restrict__ whh,
                       const float* __restrict__ bih, const float* __restrict__ bhh,
                       unsigned short* __restrict__ Wc, float* __restrict__ bp) {
    int p = blockIdx.x;
    int s = p >> 6, q = (p >> 4) & 3, hl = p & 15;
    int orig = q * H_ + s * 16 + hl;
    unsigned short* dst = Wc + (size_t)p * KTOT;
    const float* s1 = wih + (size_t)orig * E_;
    const float* s2 = whh + (size_t)orig * H_;
    int tx = threadIdx.x;
#pragma unroll
    for (int i = 0; i < 2; ++i) dst[tx + i*256] = f2b(s1[tx + i*256]);
#pragma unroll
    for (int i = 0; i < 4; ++i) dst[E_ + tx + i*256] = f2b(s2[tx + i*256]);
    if (tx == 0) bp[p] = bih[orig] + bhh[orig];
}

__global__ void prep_xe(const int* __restrict__ x, const float* __restrict__ emb,
                        unsigned short* __restrict__ xe) {
    int bid = blockIdx.x;
    int t = bid >> 6, b = bid & 63;
    int idx = x[b * T_ + t];
    const float* src = emb + (size_t)idx * E_;
    unsigned short* dst = xe + ((size_t)t * B_ + b) * E_;
    int tx = threadIdx.x;
    dst[tx] = f2b(src[tx]);
    dst[tx + 256] = f2b(src[tx + 256]);
}

__global__ void prep_h(const float* __restrict__ h0, unsigned short* __restrict__ hb) {
    int b = blockIdx.x;
#pragma unroll
    for (int i = 0; i < 4; ++i) {
        int j = threadIdx.x + i*256;
        hb[(size_t)b * H_ + j] = f2b(h0[(size_t)b * H_ + j]);
    }
}

// v3: progressive per-subline dataflow. 256 WGs = 4 groups of 64 (g = wg&3
// owns rows [16g,16g+16); s = wg>>2 -> 64 gate cols -> 16 hdims). 4 waves
// (ch, kh). Weights in AGPRs. h(t): cells stage bf16 in LDS; WAVE 0 alone
// does 32 x 16B sc-bypass stores, acks, tid0 adds subline si = s&7.
// Consumers: per-PAIR waits (frag j needs sublines 2j&7, +1 -> pair p=j&3);
// pull pair p, MFMA pair p-1 while loads fly. No release barrier.
__global__ __launch_bounds__(256, 1)
void lstm_v3(const unsigned short* __restrict__ xe,
             const unsigned short* __restrict__ Wc,
             const float* __restrict__ bp,
             const float* __restrict__ c0,
             const unsigned short* __restrict__ hb0,
             unsigned short* __restrict__ hbt,
             float* __restrict__ out,
             int* __restrict__ flags) {
    __shared__ float gpart[2][16][68];
    __shared__ unsigned short hstage[16][16];

    const int tid = threadIdx.x;
    const int wg  = blockIdx.x;
    const int g   = wg & 3;
    const int s   = wg >> 2;
    const int w = tid >> 6, l = tid & 63;
    const int ch = w >> 1, kh = w & 1;
    const int lc = l & 15;
    const int lk = (l >> 4) << 3;

    // ---- W fragments (AGPRs): j<8 xe part, j>=8 h part ----
    i32x4 wreg0[24], wreg1[24];
    {
        const unsigned short* wrow0 = Wc + (size_t)((s << 6) + (ch << 5) + lc) * KTOT;
        const unsigned short* wrow1 = wrow0 + (size_t)16 * KTOT;
#pragma unroll
        for (int j = 0; j < 8; ++j) {
            int k = (kh << 8) + j * 32 + lk;
            wreg0[j] = *(const i32x4*)(wrow0 + k);
            wreg1[j] = *(const i32x4*)(wrow1 + k);
        }
#pragma unroll
        for (int j = 0; j < 16; ++j) {
            int k = 512 + (kh << 9) + j * 32 + lk;
            wreg0[8 + j] = *(const i32x4*)(wrow0 + k);
            wreg1[8 + j] = *(const i32x4*)(wrow1 + k);
        }
    }

    const int brow = (g << 4) + lc;

    const int b_c = tid >> 4, hl_c = tid & 15;
    const int bglob = (g << 4) + b_c;
    const int hdim = (s << 4) + hl_c;
    float c = c0[(size_t)bglob * H_ + hdim];
    const float bi  = bp[(s << 6) + hl_c];
    const float bf_ = bp[(s << 6) + 16 + hl_c];
    const float bg  = bp[(s << 6) + 32 + hl_c];
    const float bo  = bp[(s << 6) + 48 + hl_c];

    int* subc = &flags[g << 10];         // 8 sub-counters, 128 B apart
    const int si = s & 7;

    i32x4 a[24];
    {   // t=0 xe frags
        const unsigned short* xp = xe + ((size_t)brow) * E_ + (kh << 8) + lk;
#pragma unroll
        for (int j = 0; j < 8; ++j) a[j] = *(const i32x4*)(xp + j * 32);
    }

    for (int t = 0; t < T_; ++t) {
        int dead = 0;
        f32x4 acc0 = {0.f, 0.f, 0.f, 0.f};
        f32x4 acc1 = {0.f, 0.f, 0.f, 0.f};

        if (t == 0) {
            const unsigned short* hp = hb0 + (size_t)brow * H_ + (kh << 9) + lk;
#pragma unroll
            for (int j = 0; j < 16; ++j) a[8 + j] = *(const i32x4*)(hp + j * 32);
            asm volatile("s_nop 3\n\tv_mfma_f32_16x16x32_bf16 %0, %1, %2, %0"
                         : "+v"(acc0) : "v"(a[0]), "a"(wreg0[0]));
            asm volatile("s_nop 3\n\tv_mfma_f32_16x16x32_bf16 %0, %1, %2, %0"
                         : "+v"(acc1) : "v"(a[0]), "a"(wreg1[0]));
#pragma unroll
            for (int j = 1; j < 24; ++j) {
                asm volatile("s_nop 1\n\tv_mfma_f32_16x16x32_bf16 %0, %1, %2, %0"
                             : "+v"(acc0) : "v"(a[j]), "a"(wreg0[j]));
                asm volatile("s_nop 1\n\tv_mfma_f32_16x16x32_bf16 %0, %1, %2, %0"
                             : "+v"(acc1) : "v"(a[j]), "a"(wreg1[j]));
            }
            {   // xe(1) prefetch
                const unsigned short* xp = xe + ((size_t)B_ + brow) * E_ + (kh << 8) + lk;
#pragma unroll
                for (int j = 0; j < 8; ++j) a[j] = *(const i32x4*)(xp + j * 32);
            }
        } else {
            const unsigned short* hpf = hbt + (size_t)(t - 1) * (B_ * H_)
                                            + (size_t)brow * H_ + (kh << 9) + lk;
            const int tgt = t << 3;
#pragma unroll
            for (int p = 0; p < 4; ++p) {
                // ---- wait sublines 2p, 2p+1 (lanes 0-1 poll) ----
                {
                    unsigned spin = 0;
                    for (;;) {
                        int v = (l < 2)
                            ? __hip_atomic_load(&subc[((p << 1) + l) << 5],
                                                __ATOMIC_RELAXED,
                                                __HIP_MEMORY_SCOPE_AGENT)
                            : tgt;
                        if (__all(v >= tgt)) break;
                        if (++spin > (1u << 17)) { dead = 1; break; }
                    }
                }
                asm volatile("" ::: "memory");  // pulls can't hoist above poll
                // ---- pull pair p: frags j = p, p+4, p+8, p+12 ----
                a[8 + p]  = *(const i32x4*)(hpf + p * 32);
                a[12 + p] = *(const i32x4*)(hpf + (p + 4) * 32);
                a[16 + p] = *(const i32x4*)(hpf + (p + 8) * 32);
                a[20 + p] = *(const i32x4*)(hpf + (p + 12) * 32);
                if (p == 0) {
                    // xe MFMAs overlap pull0's flight
                    asm volatile("s_nop 3\n\tv_mfma_f32_16x16x32_bf16 %0, %1, %2, %0"
                                 : "+v"(acc0) : "v"(a[0]), "a"(wreg0[0]));
                    asm volatile("s_nop 3\n\tv_mfma_f32_16x16x32_bf16 %0, %1, %2, %0"
                                 : "+v"(acc1) : "v"(a[0]), "a"(wreg1[0]));
#pragma unroll
                    for (int j = 1; j < 8; ++j) {
                        asm volatile("s_nop 1\n\tv_mfma_f32_16x16x32_bf16 %0, %1, %2, %0"
                                     : "+v"(acc0) : "v"(a[j]), "a"(wreg0[j]));
                        asm volatile("s_nop 1\n\tv_mfma_f32_16x16x32_bf16 %0, %1, %2, %0"
                                     : "+v"(acc1) : "v"(a[j]), "a"(wreg1[j]));
                    }
                    if (t + 1 < T_) {   // xe(t+1) prefetch, in flight from here
                        const unsigned short* xp = xe + ((size_t)(t + 1) * B_ + brow) * E_
                                                      + (kh << 8) + lk;
#pragma unroll
                        for (int j = 0; j < 8; ++j) a[j] = *(const i32x4*)(xp + j * 32);
                    }
                } else {
                    const int jj = p - 1;
#pragma unroll
                    for (int q = 0; q < 4; ++q) {
                        asm volatile("s_nop 1\n\tv_mfma_f32_16x16x32_bf16 %0, %1, %2, %0"
                                     : "+v"(acc0) : "v"(a[8 + jj + (q << 2)]), "a"(wreg0[8 + jj + (q << 2)]));
                        asm volatile("s_nop 1\n\tv_mfma_f32_16x16x32_bf16 %0, %1, %2, %0"
                                     : "+v"(acc1) : "v"(a[8 + jj + (q << 2)]), "a"(wreg1[8 + jj + (q << 2)]));
                    }
                }
            }
            // ---- MFMA pair 3 ----
#pragma unroll
            for (int q = 0; q < 4; ++q) {
                asm volatile("s_nop 1\n\tv_mfma_f32_16x16x32_bf16 %0, %1, %2, %0"
                             : "+v"(acc0) : "v"(a[11 + (q << 2)]), "a"(wreg0[11 + (q << 2)]));
                asm volatile("s_nop 1\n\tv_mfma_f32_16x16x32_bf16 %0, %1, %2, %0"
                             : "+v"(acc1) : "v"(a[11 + (q << 2)]), "a"(wreg1[11 + (q << 2)]));
            }
        }

        asm volatile("s_nop 7\n\ts_nop 7\n\ts_nop 7"
                     : "+v"(acc0), "+v"(acc1) :: "memory");  // MFMA -> read D
        {
            const int grow = (l >> 4) << 2;
            const int cb = (ch << 5) + lc;
#pragma unroll
            for (int j = 0; j < 4; ++j) {
                gpart[kh][grow + j][cb]      = acc0[j];
                gpart[kh][grow + j][cb + 16] = acc1[j];
            }
        }
        if (__syncthreads_or(dead)) break;   // gpart ready / uniform escape

        // ---- LSTM cell (one (b,hdim) per thread) ----
        float hv;
        {
            float xi = gpart[0][b_c][hl_c]      + gpart[1][b_c][hl_c]      + bi;
            float xf = gpart[0][b_c][16 + hl_c] + gpart[1][b_c][16 + hl_c] + bf_;
            float xg = gpart[0][b_c][32 + hl_c] + gpart[1][b_c][32 + hl_c] + bg;
            float xo = gpart[0][b_c][48 + hl_c] + gpart[1][b_c][48 + hl_c] + bo;
            float iv = 1.f / (1.f + __expf(-xi));
            float fv = 1.f / (1.f + __expf(-xf));
            float eg = __expf(2.f * fminf(fmaxf(xg, -15.f), 15.f));
            float gv = (eg - 1.f) / (eg + 1.f);
            float ov = 1.f / (1.f + __expf(-xo));
            c = fv * c + iv * gv;
            float ec = __expf(2.f * fminf(fmaxf(c, -15.f), 15.f));
            float th = (ec - 1.f) / (ec + 1.f);
            hv = ov * th;
        }
        hstage[b_c][hl_c] = f2b(hv);
        const size_t oidx = ((size_t)bglob * T_ + t) * H_ + hdim;
        if (w != 0) __builtin_nontemporal_store(hv, &out[oidx]);
        __syncthreads();                     // hstage ready for wave 0

        if (w == 0) {
            if (t < T_ - 1) {
                if (l < 32) {                // 32 x 16B coalesced h stores
                    const int row = l >> 1, half = l & 1;
                    i32x4 hv4 = *(const i32x4*)&hstage[row][half << 3];
                    unsigned long long ha = (unsigned long long)
                        (hbt + (size_t)t * (B_ * H_)
                             + (size_t)((g << 4) + row) * H_ + (s << 4) + (half << 3));
                    asm volatile("global_store_dwordx4 %0, %1, off sc0 sc1"
                                 :: "v"(ha), "v"(hv4) : "memory");
                }
                asm volatile("s_waitcnt vmcnt(0)" ::: "memory");  // acked
                if (tid == 0)
                    __hip_atomic_fetch_add(&subc[si << 5], 1, __ATOMIC_RELAXED,
                                           __HIP_MEMORY_SCOPE_AGENT);
            }
            __builtin_nontemporal_store(hv, &out[oidx]);   // wave0 out after add
        }
    }
}

extern "C" void kernel_launch(void* const* d_in, const int* in_sizes, int n_in,
                              void* d_out, int out_size, void* d_ws, size_t ws_size,
                              hipStream_t stream) {
    const int*   x   = (const int*)  d_in[0];
    const float* emb = (const float*)d_in[1];
    const float* wih = (const float*)d_in[2];
    const float* whh = (const float*)d_in[3];
    const float* bih = (const float*)d_in[4];
    const float* bhh = (const float*)d_in[5];
    const float* h0  = (const float*)d_in[6];
    const float* c0  = (const float*)d_in[7];
    float* out = (float*)d_out;
    char* ws = (char*)d_ws;

    unsigned short* xe  = (unsigned short*)(ws + OFF_XE);
    unsigned short* Wc  = (unsigned short*)(ws + OFF_WC);
    float*          bp  = (float*)(ws + OFF_BIAS);
    unsigned short* hb0 = (unsigned short*)(ws + OFF_H0);
    int*            flg = (int*)(ws + OFF_FLAGS);
    unsigned short* hbt = (unsigned short*)(ws + OFF_HBT);

    (void)hipMemsetAsync(flg, 0, 4096 * sizeof(int), stream);
    prep_w <<<dim3(G4_),   dim3(256), 0, stream>>>(wih, whh, bih, bhh, Wc, bp);
    prep_xe<<<dim3(B_*T_), dim3(256), 0, stream>>>(x, emb, xe);
    prep_h <<<dim3(B_),    dim3(256), 0, stream>>>(h0, hb0);

    lstm_v3<<<dim3(NWG), dim3(256), 0, stream>>>(xe, Wc, bp, c0, hb0, hbt, out, flg);
}